// Round 17
// baseline (138.925 us; speedup 1.0000x reference)
//
#include <hip/hip_runtime.h>

#define N_NODES 100000
#define D_FEAT  64
#define N_EDGES 3200000
#define GAMMA   0.5f

#define BSH   6                                   // 64 nodes per bucket
#define BN    (1 << BSH)                          // 64
#define NB    ((N_NODES + BN - 1) >> BSH)         // 1563 buckets
#define CH    2048                                // edges per chunk
#define NC    ((N_EDGES + CH - 1) / CH)           // 1563 chunks

#define Z_BLOCKS   782                            // edge-zero blocks (4 float4/thr)
#define CVT_V4     (N_NODES * D_FEAT / 4)         // 1,600,000 float4
#define CVT_BLOCKS ((CVT_V4 + 255) / 256)         // 6250

#define KG_REG   5                                // recs cached per thread (fused)
#define KG_CAP   2368                             // bucket cap (avg 2046, +7 sigma)
#define SRC_MASK 0x1FFFFu                         // 17 bits for src

// ---- P0: [per-chunk bucket hist -> mat16] | [zero edge-out] | [h->bf16] ----
__global__ void __launch_bounds__(256)
p0_kernel(const float* __restrict__ h,
          const int* __restrict__ dst,
          unsigned short* __restrict__ h16,
          unsigned short* __restrict__ mat,
          float* __restrict__ out_edge) {
    __shared__ int hist[NB];
    const int bid = blockIdx.x;
    const int t   = threadIdx.x;
    if (bid < NC) {
        for (int i = t; i < NB; i += 256) hist[i] = 0;
        __syncthreads();
        const int base  = bid * CH;
        const int chcnt = min(N_EDGES - base, CH);      // 2048 or 1024 (4-divisible)
        const int4* dst4 = (const int4*)(dst + base);
        const int nv4 = chcnt >> 2;
#pragma unroll
        for (int j = 0; j < 2; ++j) {
            int i = j * 256 + t;
            if (i < nv4) {
                int4 d = dst4[i];
                __hip_atomic_fetch_add(&hist[d.x >> BSH], 1, __ATOMIC_RELAXED, __HIP_MEMORY_SCOPE_WORKGROUP);
                __hip_atomic_fetch_add(&hist[d.y >> BSH], 1, __ATOMIC_RELAXED, __HIP_MEMORY_SCOPE_WORKGROUP);
                __hip_atomic_fetch_add(&hist[d.z >> BSH], 1, __ATOMIC_RELAXED, __HIP_MEMORY_SCOPE_WORKGROUP);
                __hip_atomic_fetch_add(&hist[d.w >> BSH], 1, __ATOMIC_RELAXED, __HIP_MEMORY_SCOPE_WORKGROUP);
            }
        }
        __syncthreads();
        for (int i = t; i < NB; i += 256)
            mat[bid * NB + i] = (unsigned short)hist[i];
    } else if (bid < NC + Z_BLOCKS) {
        float4* oe4 = (float4*)out_edge;
        const int b2 = bid - NC;
        const float4 z = make_float4(0.f, 0.f, 0.f, 0.f);
#pragma unroll
        for (int j = 0; j < 4; ++j) {
            int i = b2 * 1024 + j * 256 + t;
            if (i < N_EDGES / 4) oe4[i] = z;
        }
    } else {
        int i = (bid - NC - Z_BLOCKS) * 256 + t;
        if (i < CVT_V4) {
            float4 v = ((const float4*)h)[i];
            ushort4 o;
            unsigned u;
            u = __float_as_uint(v.x); o.x = (unsigned short)((u + 0x7fffu + ((u >> 16) & 1u)) >> 16);
            u = __float_as_uint(v.y); o.y = (unsigned short)((u + 0x7fffu + ((u >> 16) & 1u)) >> 16);
            u = __float_as_uint(v.z); o.z = (unsigned short)((u + 0x7fffu + ((u >> 16) & 1u)) >> 16);
            u = __float_as_uint(v.w); o.w = (unsigned short)((u + 0x7fffu + ((u >> 16) & 1u)) >> 16);
            ((ushort4*)h16)[i] = o;
        }
    }
}

// ---- M1: in-place exclusive scan of each bucket row across chunks ----
__global__ void __launch_bounds__(64)
matscan_kernel(unsigned short* __restrict__ mat,
               int* __restrict__ rowsum) {
    const int b = blockIdx.x;
    const int l = threadIdx.x;
    int carry = 0;
    for (int r = 0; r < (NC + 63) / 64; ++r) {
        int c = r * 64 + l;
        int v = (c < NC) ? (int)mat[c * NB + b] : 0;
        int incl = v;
        for (int s = 1; s < 64; s <<= 1) {
            int u = __shfl_up(incl, s, 64);
            if (l >= s) incl += u;
        }
        if (c < NC) mat[c * NB + b] = (unsigned short)(carry + incl - v);
        carry += __shfl(incl, 63, 64);
    }
    if (l == 0) rowsum[b] = carry;
}

// ---- K1: chunk sort + scatter, zero global atomics (positions from mat).
// 1563 bins -> 4 bins/thread shfl scans; hist reused as pos after scan.
__global__ void __launch_bounds__(512)
bucket_scatter_kernel(const int* __restrict__ src,
                      const int* __restrict__ dst,
                      const float* __restrict__ e,
                      const unsigned short* __restrict__ mat,
                      const int* __restrict__ rowsum,
                      int* __restrict__ offs_g,
                      uint2* __restrict__ recs) {
    __shared__ uint2          stage[CH];          // 16 KB
    __shared__ unsigned short bkt[CH];            // 4 KB
    __shared__ int hist[NB];                      // 6.3 KB (becomes pos)
    __shared__ int diff[NB];                      // 6.3 KB
    __shared__ int offsL[NB + 1];                 // 6.3 KB
    __shared__ int wsum[8];

    const int t    = threadIdx.x;
    const int lane = t & 63;
    const int wid  = t >> 6;
    const int c    = blockIdx.x;
    const int base = c * CH;
    const int chcnt = min(N_EDGES - base, CH);
    const int q0 = 4 * t, q1 = q0 + 1, q2 = q0 + 2, q3 = q0 + 3;

    for (int i = t; i < NB; i += 512) hist[i] = 0;
    // global offs scan from rowsum (4 bins/thread, shfl two-level)
    int a0 = (q0 < NB) ? rowsum[q0] : 0;
    int a1 = (q1 < NB) ? rowsum[q1] : 0;
    int a2 = (q2 < NB) ? rowsum[q2] : 0;
    int a3 = (q3 < NB) ? rowsum[q3] : 0;
    int s4 = a0 + a1 + a2 + a3, incl = s4;
    for (int s = 1; s < 64; s <<= 1) {
        int u = __shfl_up(incl, s, 64);
        if (lane >= s) incl += u;
    }
    if (lane == 63) wsum[wid] = incl;
    __syncthreads();
    {
        int pre = 0;
        for (int w = 0; w < wid; ++w) pre += wsum[w];
        int exc = pre + incl - s4;
        if (q0 < NB) offsL[q0] = exc;
        if (q1 < NB) offsL[q1] = exc + a0;
        if (q2 < NB) offsL[q2] = exc + a0 + a1;
        if (q3 < NB) offsL[q3] = exc + a0 + a1 + a2;
        if (t == 511) offsL[NB] = pre + incl;     // == N_EDGES
    }
    int dv[4];
#pragma unroll
    for (int j = 0; j < 4; ++j) {
        int i = j * 512 + t;
        if (i < chcnt) {
            dv[j] = dst[base + i];
            __hip_atomic_fetch_add(&hist[dv[j] >> BSH], 1,
                                   __ATOMIC_RELAXED, __HIP_MEMORY_SCOPE_WORKGROUP);
        } else dv[j] = -1;
    }
    __syncthreads();
    // local hist scan (4 bins/thread); then hist slots become pos
    int c0 = (q0 < NB) ? hist[q0] : 0;
    int c1 = (q1 < NB) ? hist[q1] : 0;
    int c2 = (q2 < NB) ? hist[q2] : 0;
    int c3 = (q3 < NB) ? hist[q3] : 0;
    int t4 = c0 + c1 + c2 + c3, incl2 = t4;
    for (int s = 1; s < 64; s <<= 1) {
        int u = __shfl_up(incl2, s, 64);
        if (lane >= s) incl2 += u;
    }
    if (lane == 63) wsum[wid] = incl2;
    __syncthreads();
    {
        int pre = 0;
        for (int w = 0; w < wid; ++w) pre += wsum[w];
        int e0 = pre + incl2 - t4;
        int e1 = e0 + c0, e2 = e1 + c1, e3 = e2 + c2;
        if (q0 < NB) { hist[q0] = e0; diff[q0] = offsL[q0] + (int)mat[c * NB + q0] - e0; }
        if (q1 < NB) { hist[q1] = e1; diff[q1] = offsL[q1] + (int)mat[c * NB + q1] - e1; }
        if (q2 < NB) { hist[q2] = e2; diff[q2] = offsL[q2] + (int)mat[c * NB + q2] - e2; }
        if (q3 < NB) { hist[q3] = e3; diff[q3] = offsL[q3] + (int)mat[c * NB + q3] - e3; }
    }
    __syncthreads();
#pragma unroll
    for (int j = 0; j < 4; ++j) {
        if (dv[j] >= 0) {
            int gi = base + j * 512 + t;
            int b  = dv[j] >> BSH;
            int p  = __hip_atomic_fetch_add(&hist[b], 1,
                            __ATOMIC_RELAXED, __HIP_MEMORY_SCOPE_WORKGROUP);
            unsigned pk = (unsigned)src[gi] | ((unsigned)(dv[j] & (BN - 1)) << 17);
            stage[p] = make_uint2(pk, __float_as_uint(e[gi]));
            bkt[p]   = (unsigned short)b;
        }
    }
    __syncthreads();
    for (int i = t; i < chcnt; i += 512) {
        recs[diff[bkt[i]] + i] = stage[i];
    }
    if (c == 0) {
        for (int i = t; i <= NB; i += 512) offs_g[i] = offsL[i];
    }
}

// ---- KG: fused [in-LDS node sort + gather]. One block per 64-node bucket.
// LDS ~19.7 KB -> 8 blocks/CU; 1563 blocks ~ 6.1/CU resident.
__global__ void __launch_bounds__(512)
sort_gather_kernel(const float* __restrict__ h,
                   const unsigned short* __restrict__ h16,
                   const int* __restrict__ offs,
                   const uint2* __restrict__ recs,
                   float* __restrict__ out) {
    __shared__ uint2 kw[KG_CAP];                  // 18944 B
    __shared__ int hist[BN], ebuf[BN], pos[BN];   // 768 B

    const int b    = blockIdx.x;
    const int t    = threadIdx.x;
    const int lane = t & 63;
    const int wid  = t >> 6;
    const int g    = lane >> 3;        // edge group 0..7
    const int sub  = lane & 7;         // uint4 slot 0..7
    const int lo   = offs[b];
    const int cnt  = offs[b + 1] - lo;

    const uint4* __restrict__ hv = (const uint4*)h16;

#define ACC_KW(kx, wx)                                                      \
    {                                                                       \
        uint4 v = hv[((kx) & SRC_MASK) * 8 + sub];                          \
        a0 += __uint_as_float(v.x << 16) * (wx);                            \
        a1 += __uint_as_float(v.x & 0xFFFF0000u) * (wx);                    \
        a2 += __uint_as_float(v.y << 16) * (wx);                            \
        a3 += __uint_as_float(v.y & 0xFFFF0000u) * (wx);                    \
        a4 += __uint_as_float(v.z << 16) * (wx);                            \
        a5 += __uint_as_float(v.z & 0xFFFF0000u) * (wx);                    \
        a6 += __uint_as_float(v.w << 16) * (wx);                            \
        a7 += __uint_as_float(v.w & 0xFFFF0000u) * (wx);                    \
    }

    if (cnt <= KG_CAP) {
        if (t < BN) hist[t] = 0;
        __syncthreads();
        // A: reg-cache recs + node histogram
        uint2 r[KG_REG];
#pragma unroll
        for (int j = 0; j < KG_REG; ++j) {
            int i = j * 512 + t;
            if (i < cnt) {
                r[j] = recs[lo + i];
                __hip_atomic_fetch_add(&hist[r[j].x >> 17], 1,
                                       __ATOMIC_RELAXED, __HIP_MEMORY_SCOPE_WORKGROUP);
            } else r[j].x = 0xFFFFFFFFu;
        }
        __syncthreads();
        // B: exclusive scan of 64 bins (wave 0 only)
        if (t < BN) {
            int c = hist[t], incl = c;
            for (int s = 1; s < 64; s <<= 1) {
                int u = __shfl_up(incl, s, 64);
                if (lane >= s) incl += u;
            }
            int exc = incl - c;
            ebuf[t] = exc;
            pos[t]  = exc;
        }
        __syncthreads();
        // C: scatter into LDS, node-sorted (pos-trick)
#pragma unroll
        for (int j = 0; j < KG_REG; ++j) {
            if (r[j].x != 0xFFFFFFFFu) {
                int dl = r[j].x >> 17;
                int p  = __hip_atomic_fetch_add(&pos[dl], 1,
                                __ATOMIC_RELAXED, __HIP_MEMORY_SCOPE_WORKGROUP);
                kw[p] = r[j];
            }
        }
        __syncthreads();
        // D: gather. wave = 8 nodes; 8 groups x 8 lanes; uint4 h16 rows.
        // pos[ln] now holds the node's END offset.
        for (int i = 0; i < 8; ++i) {
            const int ln  = wid * 8 + i;
            const int n   = (b << BSH) + ln;
            const int nlo = ebuf[ln];
            const int nhi = pos[ln];
            float a0=0.f,a1=0.f,a2=0.f,a3=0.f,a4=0.f,a5=0.f,a6=0.f,a7=0.f;
            int kk = nlo + g;
            while (kk < nhi) {
                uint2 q0 = kw[kk];
                bool m1 = kk +  8 < nhi;
                bool m2 = kk + 16 < nhi;
                bool m3 = kk + 24 < nhi;
                uint2 q1 = m1 ? kw[kk +  8] : make_uint2(0u, 0u);
                uint2 q2 = m2 ? kw[kk + 16] : make_uint2(0u, 0u);
                uint2 q3 = m3 ? kw[kk + 24] : make_uint2(0u, 0u);
                ACC_KW(q0.x, __uint_as_float(q0.y));
                ACC_KW(q1.x, __uint_as_float(q1.y));
                ACC_KW(q2.x, __uint_as_float(q2.y));
                ACC_KW(q3.x, __uint_as_float(q3.y));
                kk += 32;
            }
            for (int m = 8; m <= 32; m <<= 1) {
                a0 += __shfl_xor(a0, m); a1 += __shfl_xor(a1, m);
                a2 += __shfl_xor(a2, m); a3 += __shfl_xor(a3, m);
                a4 += __shfl_xor(a4, m); a5 += __shfl_xor(a5, m);
                a6 += __shfl_xor(a6, m); a7 += __shfl_xor(a7, m);
            }
            if (g == 0 && n < N_NODES) {
                const float4* __restrict__ h4 = (const float4*)h;
                const int o = n * 16 + sub * 2;
                float4 p = h4[o], q = h4[o + 1];
                float4 r0, r1;
                r0.x = a0 - GAMMA * p.x; r0.y = a1 - GAMMA * p.y;
                r0.z = a2 - GAMMA * p.z; r0.w = a3 - GAMMA * p.w;
                r1.x = a4 - GAMMA * q.x; r1.y = a5 - GAMMA * q.y;
                r1.z = a6 - GAMMA * q.z; r1.w = a7 - GAMMA * q.w;
                ((float4*)out)[o]     = r0;
                ((float4*)out)[o + 1] = r1;
            }
        }
    } else {
        // overflow fallback (never expected): scan-match from global recs
        for (int i = 0; i < 8; ++i) {
            const int ln = wid * 8 + i;
            const int n  = (b << BSH) + ln;
            float a0=0.f,a1=0.f,a2=0.f,a3=0.f,a4=0.f,a5=0.f,a6=0.f,a7=0.f;
            for (int k = lo + g; k < lo + cnt; k += 8) {
                uint2 rr = recs[k];
                if ((int)(rr.x >> 17) == ln) ACC_KW(rr.x, __uint_as_float(rr.y));
            }
            for (int m = 8; m <= 32; m <<= 1) {
                a0 += __shfl_xor(a0, m); a1 += __shfl_xor(a1, m);
                a2 += __shfl_xor(a2, m); a3 += __shfl_xor(a3, m);
                a4 += __shfl_xor(a4, m); a5 += __shfl_xor(a5, m);
                a6 += __shfl_xor(a6, m); a7 += __shfl_xor(a7, m);
            }
            if (g == 0 && n < N_NODES) {
                const float4* __restrict__ h4 = (const float4*)h;
                const int o = n * 16 + sub * 2;
                float4 p = h4[o], q = h4[o + 1];
                float4 r0, r1;
                r0.x = a0 - GAMMA * p.x; r0.y = a1 - GAMMA * p.y;
                r0.z = a2 - GAMMA * p.z; r0.w = a3 - GAMMA * p.w;
                r1.x = a4 - GAMMA * q.x; r1.y = a5 - GAMMA * q.y;
                r1.z = a6 - GAMMA * q.z; r1.w = a7 - GAMMA * q.w;
                ((float4*)out)[o]     = r0;
                ((float4*)out)[o + 1] = r1;
            }
        }
    }
#undef ACC_KW
}

// ---------------- fallback atomic path (if ws too small) ----------------
__global__ void init_out_kernel(const float* __restrict__ x,
                                float* __restrict__ out,
                                int nd, int total) {
    int i = blockIdx.x * blockDim.x + threadIdx.x;
    if (i < nd)         out[i] = -GAMMA * x[i];
    else if (i < total) out[i] = 0.0f;
}

__global__ void edge_scatter_kernel(const float* __restrict__ h,
                                    const float* __restrict__ e,
                                    const int* __restrict__ src,
                                    const int* __restrict__ dst,
                                    float* __restrict__ out) {
    long long idx = (long long)blockIdx.x * blockDim.x + threadIdx.x;
    int edge = (int)(idx >> 6);
    int d    = (int)(idx & 63);
    if (edge >= N_EDGES) return;
    atomicAdd(&out[dst[edge] * D_FEAT + d], h[src[edge] * D_FEAT + d] * e[edge]);
}

// ---------------- launch ----------------
extern "C" void kernel_launch(void* const* d_in, const int* in_sizes, int n_in,
                              void* d_out, int out_size, void* d_ws, size_t ws_size,
                              hipStream_t stream) {
    const float* x   = (const float*)d_in[1];
    const int*   src = (const int*)d_in[2];
    const int*   dst = (const int*)d_in[3];
    float*       out = (float*)d_out;

    const int nd = N_NODES * D_FEAT;

    // ws: offs[NB+1] | rowsum[NB] | mat16[NC*NB] | pad->256 | recs[E] | pad->256 | h16[nd]
    size_t ints    = (size_t)(NB + 1) + NB;
    size_t mat_off = ints * 4;
    size_t rec_off = (mat_off + (size_t)NC * NB * 2 + 255) & ~(size_t)255;
    size_t h16_off = (rec_off + (size_t)N_EDGES * 8 + 255) & ~(size_t)255;
    size_t needed  = h16_off + (size_t)nd * 2;

    if (ws_size >= needed) {
        int* offs   = (int*)d_ws;
        int* rowsum = offs + NB + 1;
        unsigned short* mat  = (unsigned short*)((char*)d_ws + mat_off);
        uint2*          recs = (uint2*)((char*)d_ws + rec_off);
        unsigned short* h16  = (unsigned short*)((char*)d_ws + h16_off);

        p0_kernel<<<NC + Z_BLOCKS + CVT_BLOCKS, 256, 0, stream>>>(
            x, dst, h16, mat, out + nd);
        matscan_kernel<<<NB, 64, 0, stream>>>(mat, rowsum);
        bucket_scatter_kernel<<<NC, 512, 0, stream>>>(
            src, dst, x + nd, mat, rowsum, offs, recs);
        sort_gather_kernel<<<NB, 512, 0, stream>>>(x, h16, offs, recs, out);
    } else {
        const int total = nd + N_EDGES;
        init_out_kernel<<<(total + 255) / 256, 256, 0, stream>>>(x, out, nd, total);
        long long threads = (long long)N_EDGES * 64;
        edge_scatter_kernel<<<(int)((threads + 255) / 256), 256, 0, stream>>>(
            x, x + nd, src, dst, out);
    }
}

// Round 18
// 119.786 us; speedup vs baseline: 1.1598x; 1.1598x over previous
//
#include <hip/hip_runtime.h>

#define N_NODES 100000
#define D_FEAT  64
#define N_EDGES 3200000
#define GAMMA   0.5f

#define BSH   6                                   // 64 nodes per bucket
#define BN    (1 << BSH)                          // 64
#define NB    ((N_NODES + BN - 1) >> BSH)         // 1563 buckets
#define CH    4096                                // edges per chunk
#define NC    ((N_EDGES + CH - 1) / CH)           // 782 chunks

#define Z_BLOCKS   782                            // edge-zero blocks (4 float4/thr)
#define CVT_V4     (N_NODES * D_FEAT / 4)         // 1,600,000 float4
#define CVT_BLOCKS ((CVT_V4 + 255) / 256)         // 6250

#define KG_REG   5                                // recs cached per thread (fused)
#define KG_CAP   2368                             // bucket cap (avg 2046, +7 sigma)
#define SRC_MASK 0x1FFFFu                         // 17 bits for src

// ---- P0: [per-chunk bucket hist -> mat16] | [zero edge-out] | [h->bf16] ----
__global__ void __launch_bounds__(256)
p0_kernel(const float* __restrict__ h,
          const int* __restrict__ dst,
          unsigned short* __restrict__ h16,
          unsigned short* __restrict__ mat,
          float* __restrict__ out_edge) {
    __shared__ int hist[NB];
    const int bid = blockIdx.x;
    const int t   = threadIdx.x;
    if (bid < NC) {
        for (int i = t; i < NB; i += 256) hist[i] = 0;
        __syncthreads();
        const int base  = bid * CH;
        const int chcnt = min(N_EDGES - base, CH);      // 4096 or 3072 (4-divisible)
        const int4* dst4 = (const int4*)(dst + base);
        const int nv4 = chcnt >> 2;
#pragma unroll
        for (int j = 0; j < 4; ++j) {
            int i = j * 256 + t;
            if (i < nv4) {
                int4 d = dst4[i];
                __hip_atomic_fetch_add(&hist[d.x >> BSH], 1, __ATOMIC_RELAXED, __HIP_MEMORY_SCOPE_WORKGROUP);
                __hip_atomic_fetch_add(&hist[d.y >> BSH], 1, __ATOMIC_RELAXED, __HIP_MEMORY_SCOPE_WORKGROUP);
                __hip_atomic_fetch_add(&hist[d.z >> BSH], 1, __ATOMIC_RELAXED, __HIP_MEMORY_SCOPE_WORKGROUP);
                __hip_atomic_fetch_add(&hist[d.w >> BSH], 1, __ATOMIC_RELAXED, __HIP_MEMORY_SCOPE_WORKGROUP);
            }
        }
        __syncthreads();
        for (int i = t; i < NB; i += 256)
            mat[bid * NB + i] = (unsigned short)hist[i];
    } else if (bid < NC + Z_BLOCKS) {
        float4* oe4 = (float4*)out_edge;
        const int b2 = bid - NC;
        const float4 z = make_float4(0.f, 0.f, 0.f, 0.f);
#pragma unroll
        for (int j = 0; j < 4; ++j) {
            int i = b2 * 1024 + j * 256 + t;
            if (i < N_EDGES / 4) oe4[i] = z;
        }
    } else {
        int i = (bid - NC - Z_BLOCKS) * 256 + t;
        if (i < CVT_V4) {
            float4 v = ((const float4*)h)[i];
            ushort4 o;
            unsigned u;
            u = __float_as_uint(v.x); o.x = (unsigned short)((u + 0x7fffu + ((u >> 16) & 1u)) >> 16);
            u = __float_as_uint(v.y); o.y = (unsigned short)((u + 0x7fffu + ((u >> 16) & 1u)) >> 16);
            u = __float_as_uint(v.z); o.z = (unsigned short)((u + 0x7fffu + ((u >> 16) & 1u)) >> 16);
            u = __float_as_uint(v.w); o.w = (unsigned short)((u + 0x7fffu + ((u >> 16) & 1u)) >> 16);
            ((ushort4*)h16)[i] = o;
        }
    }
}

// ---- M1: in-place exclusive scan of each bucket row across chunks ----
__global__ void __launch_bounds__(64)
matscan_kernel(unsigned short* __restrict__ mat,
               int* __restrict__ rowsum) {
    const int b = blockIdx.x;
    const int l = threadIdx.x;
    int carry = 0;
    for (int r = 0; r < (NC + 63) / 64; ++r) {
        int c = r * 64 + l;
        int v = (c < NC) ? (int)mat[c * NB + b] : 0;
        int incl = v;
        for (int s = 1; s < 64; s <<= 1) {
            int u = __shfl_up(incl, s, 64);
            if (l >= s) incl += u;
        }
        if (c < NC) mat[c * NB + b] = (unsigned short)(carry + incl - v);
        carry += __shfl(incl, 63, 64);
    }
    if (l == 0) rowsum[b] = carry;
}

// ---- K1: chunk sort + scatter, zero global atomics (positions from mat).
// 1024 threads, 4096-edge chunks; 59 KB LDS -> 2 blocks/CU = 100% occupancy.
__global__ void __launch_bounds__(1024)
bucket_scatter_kernel(const int* __restrict__ src,
                      const int* __restrict__ dst,
                      const float* __restrict__ e,
                      const unsigned short* __restrict__ mat,
                      const int* __restrict__ rowsum,
                      int* __restrict__ offs_g,
                      uint2* __restrict__ recs) {
    __shared__ uint2          stage[CH];          // 32 KB
    __shared__ unsigned short bkt[CH];            // 8 KB
    __shared__ int hist[NB];                      // 6.3 KB (becomes pos)
    __shared__ int diff[NB];                      // 6.3 KB
    __shared__ int offsL[NB + 1];                 // 6.3 KB
    __shared__ int wsum[16];

    const int t    = threadIdx.x;
    const int lane = t & 63;
    const int wid  = t >> 6;
    const int c    = blockIdx.x;
    const int base = c * CH;
    const int chcnt = min(N_EDGES - base, CH);
    const int i0 = 2 * t, i1 = 2 * t + 1;

    for (int i = t; i < NB; i += 1024) hist[i] = 0;
    // global offs scan from rowsum (2 bins/thread, shfl two-level, 16 waves)
    int a  = (i0 < NB) ? rowsum[i0] : 0;
    int d1 = (i1 < NB) ? rowsum[i1] : 0;
    int pair = a + d1, incl = pair;
    for (int s = 1; s < 64; s <<= 1) {
        int u = __shfl_up(incl, s, 64);
        if (lane >= s) incl += u;
    }
    if (lane == 63) wsum[wid] = incl;
    __syncthreads();
    {
        int pre = 0;
        for (int w = 0; w < wid; ++w) pre += wsum[w];
        int excl = pre + incl - pair;
        if (i0 < NB) offsL[i0] = excl;
        if (i1 < NB) offsL[i1] = excl + a;
        if (t == 1023) offsL[NB] = pre + incl;    // == N_EDGES
    }
    int dv[4];
#pragma unroll
    for (int j = 0; j < 4; ++j) {
        int i = j * 1024 + t;
        if (i < chcnt) {
            dv[j] = dst[base + i];
            __hip_atomic_fetch_add(&hist[dv[j] >> BSH], 1,
                                   __ATOMIC_RELAXED, __HIP_MEMORY_SCOPE_WORKGROUP);
        } else dv[j] = -1;
    }
    __syncthreads();
    // local hist scan (2 bins/thread); then hist slots become pos
    int c0 = (i0 < NB) ? hist[i0] : 0;
    int c1 = (i1 < NB) ? hist[i1] : 0;
    int p2 = c0 + c1, incl2 = p2;
    for (int s = 1; s < 64; s <<= 1) {
        int u = __shfl_up(incl2, s, 64);
        if (lane >= s) incl2 += u;
    }
    if (lane == 63) wsum[wid] = incl2;
    __syncthreads();
    {
        int pre = 0;
        for (int w = 0; w < wid; ++w) pre += wsum[w];
        int e0 = pre + incl2 - p2;
        int e1 = e0 + c0;
        if (i0 < NB) { hist[i0] = e0; diff[i0] = offsL[i0] + (int)mat[c * NB + i0] - e0; }
        if (i1 < NB) { hist[i1] = e1; diff[i1] = offsL[i1] + (int)mat[c * NB + i1] - e1; }
    }
    __syncthreads();
#pragma unroll
    for (int j = 0; j < 4; ++j) {
        if (dv[j] >= 0) {
            int gi = base + j * 1024 + t;
            int b  = dv[j] >> BSH;
            int p  = __hip_atomic_fetch_add(&hist[b], 1,
                            __ATOMIC_RELAXED, __HIP_MEMORY_SCOPE_WORKGROUP);
            unsigned pk = (unsigned)src[gi] | ((unsigned)(dv[j] & (BN - 1)) << 17);
            stage[p] = make_uint2(pk, __float_as_uint(e[gi]));
            bkt[p]   = (unsigned short)b;
        }
    }
    __syncthreads();
    for (int i = t; i < chcnt; i += 1024) {
        recs[diff[bkt[i]] + i] = stage[i];
    }
    if (c == 0) {
        for (int i = t; i <= NB; i += 1024) offs_g[i] = offsL[i];
    }
}

// ---- KG: fused [in-LDS node sort + gather]. One block per 64-node bucket.
// LDS ~19.7 KB; 1563 blocks; proven 60.8 us in R17 (unchanged).
__global__ void __launch_bounds__(512)
sort_gather_kernel(const float* __restrict__ h,
                   const unsigned short* __restrict__ h16,
                   const int* __restrict__ offs,
                   const uint2* __restrict__ recs,
                   float* __restrict__ out) {
    __shared__ uint2 kw[KG_CAP];                  // 18944 B
    __shared__ int hist[BN], ebuf[BN], pos[BN];   // 768 B

    const int b    = blockIdx.x;
    const int t    = threadIdx.x;
    const int lane = t & 63;
    const int wid  = t >> 6;
    const int g    = lane >> 3;        // edge group 0..7
    const int sub  = lane & 7;         // uint4 slot 0..7
    const int lo   = offs[b];
    const int cnt  = offs[b + 1] - lo;

    const uint4* __restrict__ hv = (const uint4*)h16;

#define ACC_KW(kx, wx)                                                      \
    {                                                                       \
        uint4 v = hv[((kx) & SRC_MASK) * 8 + sub];                          \
        a0 += __uint_as_float(v.x << 16) * (wx);                            \
        a1 += __uint_as_float(v.x & 0xFFFF0000u) * (wx);                    \
        a2 += __uint_as_float(v.y << 16) * (wx);                            \
        a3 += __uint_as_float(v.y & 0xFFFF0000u) * (wx);                    \
        a4 += __uint_as_float(v.z << 16) * (wx);                            \
        a5 += __uint_as_float(v.z & 0xFFFF0000u) * (wx);                    \
        a6 += __uint_as_float(v.w << 16) * (wx);                            \
        a7 += __uint_as_float(v.w & 0xFFFF0000u) * (wx);                    \
    }

    if (cnt <= KG_CAP) {
        if (t < BN) hist[t] = 0;
        __syncthreads();
        // A: reg-cache recs + node histogram
        uint2 r[KG_REG];
#pragma unroll
        for (int j = 0; j < KG_REG; ++j) {
            int i = j * 512 + t;
            if (i < cnt) {
                r[j] = recs[lo + i];
                __hip_atomic_fetch_add(&hist[r[j].x >> 17], 1,
                                       __ATOMIC_RELAXED, __HIP_MEMORY_SCOPE_WORKGROUP);
            } else r[j].x = 0xFFFFFFFFu;
        }
        __syncthreads();
        // B: exclusive scan of 64 bins (wave 0 only)
        if (t < BN) {
            int c = hist[t], incl = c;
            for (int s = 1; s < 64; s <<= 1) {
                int u = __shfl_up(incl, s, 64);
                if (lane >= s) incl += u;
            }
            int exc = incl - c;
            ebuf[t] = exc;
            pos[t]  = exc;
        }
        __syncthreads();
        // C: scatter into LDS, node-sorted (pos-trick)
#pragma unroll
        for (int j = 0; j < KG_REG; ++j) {
            if (r[j].x != 0xFFFFFFFFu) {
                int dl = r[j].x >> 17;
                int p  = __hip_atomic_fetch_add(&pos[dl], 1,
                                __ATOMIC_RELAXED, __HIP_MEMORY_SCOPE_WORKGROUP);
                kw[p] = r[j];
            }
        }
        __syncthreads();
        // D: gather. wave = 8 nodes; 8 groups x 8 lanes; uint4 h16 rows.
        for (int i = 0; i < 8; ++i) {
            const int ln  = wid * 8 + i;
            const int n   = (b << BSH) + ln;
            const int nlo = ebuf[ln];
            const int nhi = pos[ln];
            float a0=0.f,a1=0.f,a2=0.f,a3=0.f,a4=0.f,a5=0.f,a6=0.f,a7=0.f;
            int kk = nlo + g;
            while (kk < nhi) {
                uint2 q0 = kw[kk];
                bool m1 = kk +  8 < nhi;
                bool m2 = kk + 16 < nhi;
                bool m3 = kk + 24 < nhi;
                uint2 q1 = m1 ? kw[kk +  8] : make_uint2(0u, 0u);
                uint2 q2 = m2 ? kw[kk + 16] : make_uint2(0u, 0u);
                uint2 q3 = m3 ? kw[kk + 24] : make_uint2(0u, 0u);
                ACC_KW(q0.x, __uint_as_float(q0.y));
                ACC_KW(q1.x, __uint_as_float(q1.y));
                ACC_KW(q2.x, __uint_as_float(q2.y));
                ACC_KW(q3.x, __uint_as_float(q3.y));
                kk += 32;
            }
            for (int m = 8; m <= 32; m <<= 1) {
                a0 += __shfl_xor(a0, m); a1 += __shfl_xor(a1, m);
                a2 += __shfl_xor(a2, m); a3 += __shfl_xor(a3, m);
                a4 += __shfl_xor(a4, m); a5 += __shfl_xor(a5, m);
                a6 += __shfl_xor(a6, m); a7 += __shfl_xor(a7, m);
            }
            if (g == 0 && n < N_NODES) {
                const float4* __restrict__ h4 = (const float4*)h;
                const int o = n * 16 + sub * 2;
                float4 p = h4[o], q = h4[o + 1];
                float4 r0, r1;
                r0.x = a0 - GAMMA * p.x; r0.y = a1 - GAMMA * p.y;
                r0.z = a2 - GAMMA * p.z; r0.w = a3 - GAMMA * p.w;
                r1.x = a4 - GAMMA * q.x; r1.y = a5 - GAMMA * q.y;
                r1.z = a6 - GAMMA * q.z; r1.w = a7 - GAMMA * q.w;
                ((float4*)out)[o]     = r0;
                ((float4*)out)[o + 1] = r1;
            }
        }
    } else {
        // overflow fallback (never expected): scan-match from global recs
        for (int i = 0; i < 8; ++i) {
            const int ln = wid * 8 + i;
            const int n  = (b << BSH) + ln;
            float a0=0.f,a1=0.f,a2=0.f,a3=0.f,a4=0.f,a5=0.f,a6=0.f,a7=0.f;
            for (int k = lo + g; k < lo + cnt; k += 8) {
                uint2 rr = recs[k];
                if ((int)(rr.x >> 17) == ln) ACC_KW(rr.x, __uint_as_float(rr.y));
            }
            for (int m = 8; m <= 32; m <<= 1) {
                a0 += __shfl_xor(a0, m); a1 += __shfl_xor(a1, m);
                a2 += __shfl_xor(a2, m); a3 += __shfl_xor(a3, m);
                a4 += __shfl_xor(a4, m); a5 += __shfl_xor(a5, m);
                a6 += __shfl_xor(a6, m); a7 += __shfl_xor(a7, m);
            }
            if (g == 0 && n < N_NODES) {
                const float4* __restrict__ h4 = (const float4*)h;
                const int o = n * 16 + sub * 2;
                float4 p = h4[o], q = h4[o + 1];
                float4 r0, r1;
                r0.x = a0 - GAMMA * p.x; r0.y = a1 - GAMMA * p.y;
                r0.z = a2 - GAMMA * p.z; r0.w = a3 - GAMMA * p.w;
                r1.x = a4 - GAMMA * q.x; r1.y = a5 - GAMMA * q.y;
                r1.z = a6 - GAMMA * q.z; r1.w = a7 - GAMMA * q.w;
                ((float4*)out)[o]     = r0;
                ((float4*)out)[o + 1] = r1;
            }
        }
    }
#undef ACC_KW
}

// ---------------- fallback atomic path (if ws too small) ----------------
__global__ void init_out_kernel(const float* __restrict__ x,
                                float* __restrict__ out,
                                int nd, int total) {
    int i = blockIdx.x * blockDim.x + threadIdx.x;
    if (i < nd)         out[i] = -GAMMA * x[i];
    else if (i < total) out[i] = 0.0f;
}

__global__ void edge_scatter_kernel(const float* __restrict__ h,
                                    const float* __restrict__ e,
                                    const int* __restrict__ src,
                                    const int* __restrict__ dst,
                                    float* __restrict__ out) {
    long long idx = (long long)blockIdx.x * blockDim.x + threadIdx.x;
    int edge = (int)(idx >> 6);
    int d    = (int)(idx & 63);
    if (edge >= N_EDGES) return;
    atomicAdd(&out[dst[edge] * D_FEAT + d], h[src[edge] * D_FEAT + d] * e[edge]);
}

// ---------------- launch ----------------
extern "C" void kernel_launch(void* const* d_in, const int* in_sizes, int n_in,
                              void* d_out, int out_size, void* d_ws, size_t ws_size,
                              hipStream_t stream) {
    const float* x   = (const float*)d_in[1];
    const int*   src = (const int*)d_in[2];
    const int*   dst = (const int*)d_in[3];
    float*       out = (float*)d_out;

    const int nd = N_NODES * D_FEAT;

    // ws: offs[NB+1] | rowsum[NB] | mat16[NC*NB] | pad->256 | recs[E] | pad->256 | h16[nd]
    size_t ints    = (size_t)(NB + 1) + NB;
    size_t mat_off = ints * 4;
    size_t rec_off = (mat_off + (size_t)NC * NB * 2 + 255) & ~(size_t)255;
    size_t h16_off = (rec_off + (size_t)N_EDGES * 8 + 255) & ~(size_t)255;
    size_t needed  = h16_off + (size_t)nd * 2;

    if (ws_size >= needed) {
        int* offs   = (int*)d_ws;
        int* rowsum = offs + NB + 1;
        unsigned short* mat  = (unsigned short*)((char*)d_ws + mat_off);
        uint2*          recs = (uint2*)((char*)d_ws + rec_off);
        unsigned short* h16  = (unsigned short*)((char*)d_ws + h16_off);

        p0_kernel<<<NC + Z_BLOCKS + CVT_BLOCKS, 256, 0, stream>>>(
            x, dst, h16, mat, out + nd);
        matscan_kernel<<<NB, 64, 0, stream>>>(mat, rowsum);
        bucket_scatter_kernel<<<NC, 1024, 0, stream>>>(
            src, dst, x + nd, mat, rowsum, offs, recs);
        sort_gather_kernel<<<NB, 512, 0, stream>>>(x, h16, offs, recs, out);
    } else {
        const int total = nd + N_EDGES;
        init_out_kernel<<<(total + 255) / 256, 256, 0, stream>>>(x, out, nd, total);
        long long threads = (long long)N_EDGES * 64;
        edge_scatter_kernel<<<(int)((threads + 255) / 256), 256, 0, stream>>>(
            x, x + nd, src, dst, out);
    }
}